// Round 9
// baseline (494.039 us; speedup 1.0000x reference)
//
#include <hip/hip_runtime.h>
#include <hip/hip_cooperative_groups.h>
#include <stdint.h>

namespace cg = cooperative_groups;

#define M_TOT 16384      // B*S = 4*4096
#define K_DIM 2048
#define N_DIM 2048
#define W_ELEMS (N_DIM * K_DIM)   // 4194304

typedef int v4i  __attribute__((ext_vector_type(4)));

// ---------------- async global -> LDS, 16B per lane ----------------
__device__ __forceinline__ void async_load16(const void* gptr, void* lptr) {
    __builtin_amdgcn_global_load_lds(
        (__attribute__((address_space(1))) void*)(uintptr_t)gptr,
        (__attribute__((address_space(3))) void*)(uint32_t)(uintptr_t)lptr,
        16, 0, 0);
}

__device__ __forceinline__ int qclamp(float v, int lo, int hi) {
    int q = (int)rintf(v);
    q = q > hi ? hi : (q < lo ? lo : q);
    return q & 255;
}

// ---------------- fused pre-pass: wsum + wabs + wquant + xquant ----------------
// One cooperative kernel replaces 3 dependent dispatches (R8 post-mortem: the
// ~180us non-GEMM residual is launch/serialization overhead, invariant under 4
// kernel rewrites -- so cut dispatch count, not kernel work).
// Grid 1024x256 (4 blocks/CU, 16 waves/CU -- trivially co-resident for
// cooperative launch; __launch_bounds__(256,4) caps VGPR at 128).
// Phase A: per-block partial sum of w          -> spart[1024]   grid.sync()
// Phase B: all blocks reduce spart -> mean; per-block abs partials -> apart[1024]
//          grid.sync()  (grid.sync provides device-scope ordering, G16)
// Phase C: reduce apart -> wscale; quantize w (row-major) + x (wave-per-row).
// All reduction math double-precision, identical to the passing split kernels.
__global__ __launch_bounds__(256, 4) void pre_kernel(
    const float* __restrict__ x, const float* __restrict__ w,
    double* __restrict__ spart, double* __restrict__ apart,
    int8_t* __restrict__ xq, int8_t* __restrict__ wq,
    float* __restrict__ xscale, float* __restrict__ wsf)
{
    const int t  = threadIdx.x;
    const int b  = blockIdx.x;                 // 0..1023
    const int gt = b * 256 + t;                // 0..262143
    const float4* w4 = (const float4*)w;
    __shared__ double ls[4];

    // ---- Phase A: per-block partial sum of w (4 float4/thread, exact cover) ----
    double s = 0.0;
    #pragma unroll
    for (int i = 0; i < 4; i++) {
        float4 v = w4[gt + i * 262144];
        s += (double)v.x + (double)v.y + (double)v.z + (double)v.w;
    }
    #pragma unroll
    for (int off = 32; off; off >>= 1) s += __shfl_down(s, off);
    if ((t & 63) == 0) ls[t >> 6] = s;
    __syncthreads();
    if (t == 0) spart[b] = ls[0] + ls[1] + ls[2] + ls[3];
    cg::this_grid().sync();

    // ---- Phase B: mean from spart (redundant per block); abs partials ----
    double sm = spart[t] + spart[t + 256] + spart[t + 512] + spart[t + 768];
    #pragma unroll
    for (int off = 32; off; off >>= 1) sm += __shfl_down(sm, off);
    __syncthreads();                           // guard ls reuse
    if ((t & 63) == 0) ls[t >> 6] = sm;
    __syncthreads();
    const double mean = (ls[0] + ls[1] + ls[2] + ls[3]) * (1.0 / (double)W_ELEMS);
    double a = 0.0;
    #pragma unroll
    for (int i = 0; i < 4; i++) {
        float4 v = w4[gt + i * 262144];        // L3-hot second read
        a += fabs((double)v.x - mean) + fabs((double)v.y - mean) +
             fabs((double)v.z - mean) + fabs((double)v.w - mean);
    }
    #pragma unroll
    for (int off = 32; off; off >>= 1) a += __shfl_down(a, off);
    __syncthreads();
    if ((t & 63) == 0) ls[t >> 6] = a;
    __syncthreads();
    if (t == 0) apart[b] = ls[0] + ls[1] + ls[2] + ls[3];
    cg::this_grid().sync();

    // ---- Phase C: wscale from apart; quantize w and x ----
    double am = apart[t] + apart[t + 256] + apart[t + 512] + apart[t + 768];
    #pragma unroll
    for (int off = 32; off; off >>= 1) am += __shfl_down(am, off);
    __syncthreads();
    if ((t & 63) == 0) ls[t >> 6] = am;
    __syncthreads();
    const float wscale = (float)fmax(
        (ls[0] + ls[1] + ls[2] + ls[3]) * (1.0 / (double)W_ELEMS), 1e-5);
    const float fmean = (float)mean;
    if (b == 0 && t == 0) wsf[0] = wscale * (1.0f / 127.0f);

    // w-quant, row-major (R7 GEMM stages B from row-major wq)
    #pragma unroll
    for (int i = 0; i < 4; i++) {
        const int f = gt + i * 262144;
        float4 v = w4[f];                      // L3-hot third read
        int p = qclamp((v.x - fmean) / wscale, -1, 1)
              | (qclamp((v.y - fmean) / wscale, -1, 1) << 8)
              | (qclamp((v.z - fmean) / wscale, -1, 1) << 16)
              | (qclamp((v.w - fmean) / wscale, -1, 1) << 24);
        ((int*)wq)[f] = p;
    }

    // x-quant: block b owns rows [16b, 16b+16); each wave does 4 rows
    const int wv = t >> 6, lane = t & 63;
    for (int it = 0; it < 4; it++) {
        const int row = (b << 4) + (wv << 2) + it;
        const float4* xr = (const float4*)(x + (size_t)row * K_DIM);
        float4 v[8];
        #pragma unroll
        for (int i = 0; i < 8; i++) v[i] = xr[lane + (i << 6)];
        float m = 0.0f;
        #pragma unroll
        for (int i = 0; i < 8; i++)
            m = fmaxf(m, fmaxf(fmaxf(fabsf(v[i].x), fabsf(v[i].y)),
                               fmaxf(fabsf(v[i].z), fabsf(v[i].w))));
        #pragma unroll
        for (int off = 32; off; off >>= 1) m = fmaxf(m, __shfl_xor(m, off));
        const float scale = fmaxf(m, 1e-5f);
        if (lane == 0) xscale[row] = scale;
        int* outp = (int*)(xq + (size_t)row * K_DIM);
        #pragma unroll
        for (int i = 0; i < 8; i++) {
            int p = qclamp(v[i].x / scale * 127.0f, -128, 127)
                  | (qclamp(v[i].y / scale * 127.0f, -128, 127) << 8)
                  | (qclamp(v[i].z / scale * 127.0f, -128, 127) << 16)
                  | (qclamp(v[i].w / scale * 127.0f, -128, 127) << 24);
            outp[lane + (i << 6)] = p;
        }
    }
}

// ---------------- int8 GEMM: R7 verbatim (best measured: 85.6-86.6us) ----------
// 256x256 tile, BK=64, 8 waves, 3 LDS buffers, one barrier + counted vmcnt(4)
// per tile, proven-0-conflict 16-row fragments with chunk-slot swizzle
// s = c ^ ((r>>1)&3) applied on the global source.
__global__ __launch_bounds__(512, 2) void gemm_i8_kernel(
    const int8_t* __restrict__ xq, const int8_t* __restrict__ wq,
    const float* __restrict__ xscale, const float* __restrict__ wsf,
    float* __restrict__ out)
{
    __shared__ __align__(16) int8_t lsA[3][16384];   // [buf][row*64 + slot*16]
    __shared__ __align__(16) int8_t lsB[3][16384];

    const int tid  = threadIdx.x;
    const int lane = tid & 63;
    const int wv   = tid >> 6;

    // bijective XCD swizzle: 512 wgs, 64/XCD; XCD x owns bm in [8x,8x+8), bn fastest
    const int flat = blockIdx.x;
    const int nf   = ((flat & 7) << 6) | (flat >> 3);
    const int bm   = nf >> 3;                        // 0..63
    const int bn   = nf & 7;                         // 0..7

    const int sChunk = (((tid & 3) ^ ((tid >> 3) & 3)) << 4);
    const int8_t* gAb = xq + (size_t)(bm * 256 + (tid >> 2)) * K_DIM + sChunk;
    const int8_t* gBb = wq + (size_t)(bn * 256 + (tid >> 2)) * K_DIM + sChunk;

    #define STAGE(NB, T)                                                       \
        do {                                                                   \
            async_load16(gAb + ((size_t)(T) << 6),                       lsA[NB] + tid * 16); \
            async_load16(gAb + ((size_t)(T) << 6) + (size_t)128 * K_DIM, lsA[NB] + 8192 + tid * 16); \
            async_load16(gBb + ((size_t)(T) << 6),                       lsB[NB] + tid * 16); \
            async_load16(gBb + ((size_t)(T) << 6) + (size_t)128 * K_DIM, lsB[NB] + 8192 + tid * 16); \
        } while (0)

    const int wm = (wv >> 2) << 7;                   // 0 / 128
    const int wn = (wv & 3) << 6;                    // 0 / 64 / 128 / 192
    const int fr = lane & 15;
    const int fc = lane >> 4;                        // 16B k-chunk 0..3
    int aoff[8], boff[4];
    #pragma unroll
    for (int mi = 0; mi < 8; mi++) {
        int ra = wm + mi * 16 + fr;
        aoff[mi] = ra * 64 + ((fc ^ ((ra >> 1) & 3)) << 4);
    }
    #pragma unroll
    for (int nj = 0; nj < 4; nj++) {
        int rb = wn + nj * 16 + fr;
        boff[nj] = rb * 64 + ((fc ^ ((rb >> 1) & 3)) << 4);
    }

    v4i acc[8][4] = {};

    #define COMPUTE(CB)                                                        \
        do {                                                                   \
            v4i af[8], bf[4];                                                  \
            _Pragma("unroll")                                                  \
            for (int mi_ = 0; mi_ < 8; mi_++)                                  \
                af[mi_] = *(const v4i*)(lsA[CB] + aoff[mi_]);                  \
            _Pragma("unroll")                                                  \
            for (int nj_ = 0; nj_ < 4; nj_++)                                  \
                bf[nj_] = *(const v4i*)(lsB[CB] + boff[nj_]);                  \
            __builtin_amdgcn_s_setprio(1);                                     \
            _Pragma("unroll")                                                  \
            for (int mi_ = 0; mi_ < 8; mi_++)                                  \
                _Pragma("unroll")                                              \
                for (int nj_ = 0; nj_ < 4; nj_++)                              \
                    acc[mi_][nj_] = __builtin_amdgcn_mfma_i32_16x16x64_i8(     \
                        af[mi_], bf[nj_], acc[mi_][nj_], 0, 0, 0);             \
            __builtin_amdgcn_s_setprio(0);                                     \
        } while (0)

    #define TILE_MID(CB, NB, T)                                                \
        do {                                                                   \
            STAGE(NB, (T) + 2);                                                \
            COMPUTE(CB);                                                       \
            asm volatile("s_waitcnt vmcnt(4)" ::: "memory");                   \
            __builtin_amdgcn_s_barrier();                                      \
        } while (0)

    STAGE(0, 0);
    STAGE(1, 1);
    asm volatile("s_waitcnt vmcnt(4)" ::: "memory");
    __builtin_amdgcn_s_barrier();

    for (int tt = 0; tt < 30; tt += 3) {
        TILE_MID(0, 2, tt);
        TILE_MID(1, 0, tt + 1);
        TILE_MID(2, 1, tt + 2);
    }
    COMPUTE(0);
    asm volatile("s_waitcnt vmcnt(0)" ::: "memory");
    __builtin_amdgcn_s_barrier();
    COMPUTE(1);

    #undef TILE_MID
    #undef COMPUTE
    #undef STAGE

    // epilogue: dequant. 16x16 C/D: col = lane&15, row = (lane>>4)*4 + reg
    const float f127 = wsf[0];
    #pragma unroll
    for (int mi = 0; mi < 8; mi++) {
        #pragma unroll
        for (int rg = 0; rg < 4; rg++) {
            const int mg = bm * 256 + wm + mi * 16 + (lane >> 4) * 4 + rg;
            const float fs = f127 * xscale[mg];
            float* orow = out + (size_t)mg * N_DIM + bn * 256 + wn;
            #pragma unroll
            for (int nj = 0; nj < 4; nj++)
                orow[nj * 16 + fr] = fs * (float)acc[mi][nj][rg];
        }
    }
}

extern "C" void kernel_launch(void* const* d_in, const int* in_sizes, int n_in,
                              void* d_out, int out_size, void* d_ws, size_t ws_size,
                              hipStream_t stream) {
    const float* x = (const float*)d_in[0];
    const float* w = (const float*)d_in[1];
    float* out = (float*)d_out;

    char* ws = (char*)d_ws;
    double* spart  = (double*)ws;                    // 8 KB (1024 doubles)
    double* apart  = (double*)(ws + 8192);           // 8 KB
    float*  wsf    = (float*)(ws + 16384);           // 4 B
    float*  xscale = (float*)(ws + 20480);           // 64 KB
    int8_t* xq     = (int8_t*)(ws + 20480 + 65536);  // 32 MB
    int8_t* wq     = xq + (size_t)M_TOT * K_DIM;     // 4 MB (row-major)

    void* args[] = {(void*)&x, (void*)&w, (void*)&spart, (void*)&apart,
                    (void*)&xq, (void*)&wq, (void*)&xscale, (void*)&wsf};
    hipLaunchCooperativeKernel((void*)pre_kernel, dim3(1024), dim3(256),
                               args, 0, stream);
    gemm_i8_kernel<<<512, 512, 0, stream>>>(xq, wq, xscale, wsf, out);
}

// Round 10
// 303.271 us; speedup vs baseline: 1.6290x; 1.6290x over previous
//
#include <hip/hip_runtime.h>
#include <stdint.h>

#define M_TOT 16384      // B*S = 4*4096
#define K_DIM 2048
#define N_DIM 2048
#define W_ELEMS (N_DIM * K_DIM)   // 4194304

typedef int v4i  __attribute__((ext_vector_type(4)));

// ---------------- async global -> LDS, 16B per lane ----------------
__device__ __forceinline__ void async_load16(const void* gptr, void* lptr) {
    __builtin_amdgcn_global_load_lds(
        (__attribute__((address_space(1))) void*)(uintptr_t)gptr,
        (__attribute__((address_space(3))) void*)(uint32_t)(uintptr_t)lptr,
        16, 0, 0);
}

__device__ __forceinline__ int qclamp(float v, int lo, int hi) {
    int q = (int)rintf(v);
    q = q > hi ? hi : (q < lo ? lo : q);
    return q & 255;
}

// ---------------- K1: per-block weight sum partials ----------------
__global__ __launch_bounds__(256) void wsum_kernel(const float* __restrict__ w,
                                                   double* __restrict__ spart) {
    int tid = blockIdx.x * 256 + threadIdx.x;
    const float4* w4 = (const float4*)w;
    double s = 0.0;
    #pragma unroll
    for (int it = 0; it < 8; it++) {               // 512*256*8 float4 = W_ELEMS/4 exact
        float4 v = w4[tid + it * 131072];
        s += (double)v.x + (double)v.y + (double)v.z + (double)v.w;
    }
    #pragma unroll
    for (int off = 32; off; off >>= 1) s += __shfl_down(s, off);
    __shared__ double ls[4];
    if ((threadIdx.x & 63) == 0) ls[threadIdx.x >> 6] = s;
    __syncthreads();
    if (threadIdx.x == 0) spart[blockIdx.x] = ls[0] + ls[1] + ls[2] + ls[3];
}

// ---------------- K2: per-block sum |w - mean| partials ----------------
__global__ __launch_bounds__(256) void wabs_kernel(const float* __restrict__ w,
                                                   const double* __restrict__ spart,
                                                   double* __restrict__ apart) {
    __shared__ double ls[4];
    double sm = spart[threadIdx.x] + spart[threadIdx.x + 256];
    #pragma unroll
    for (int off = 32; off; off >>= 1) sm += __shfl_down(sm, off);
    if ((threadIdx.x & 63) == 0) ls[threadIdx.x >> 6] = sm;
    __syncthreads();
    double mean = (ls[0] + ls[1] + ls[2] + ls[3]) * (1.0 / (double)W_ELEMS);
    __syncthreads();                                // ls reused below
    int tid = blockIdx.x * 256 + threadIdx.x;
    const float4* w4 = (const float4*)w;
    double s = 0.0;
    #pragma unroll
    for (int it = 0; it < 8; it++) {
        float4 v = w4[tid + it * 131072];
        s += fabs((double)v.x - mean) + fabs((double)v.y - mean) +
             fabs((double)v.z - mean) + fabs((double)v.w - mean);
    }
    #pragma unroll
    for (int off = 32; off; off >>= 1) s += __shfl_down(s, off);
    if ((threadIdx.x & 63) == 0) ls[threadIdx.x >> 6] = s;
    __syncthreads();
    if (threadIdx.x == 0) apart[blockIdx.x] = ls[0] + ls[1] + ls[2] + ls[3];
}

// ---------------- K3: fused x-quant (blocks 0..4095) + w-quant (4096..5119) ----
// R9 ledger: total = ~150us fixed + sum(kernels); quant was ~55us vs 29us
// traffic floor. Fixes (both R6-verified numerically): (a) one reciprocal per
// row, multiplies elsewhere (kills ~200 VALU div-ops/lane); (b) each lane owns
// CONTIGUOUS 64B chunks so quantized output is written as int4 (16B/lane),
// 8->2 stores (xquant) and 4->1 (wquant).
__global__ __launch_bounds__(256) void quant_kernel(
    const float* __restrict__ x, const float* __restrict__ w,
    const double* __restrict__ spart, const double* __restrict__ apart,
    int8_t* __restrict__ xq, int8_t* __restrict__ wq,
    float* __restrict__ xscale, float* __restrict__ wsf)
{
    const int t = threadIdx.x;
    if (blockIdx.x < 4096) {
        // ---- per-row absmax int8 quant of x: one wave per row ----
        // lane l owns float4 idx {4l..4l+3} and {256+4l..256+4l+3} (contiguous 64B x2)
        const int row  = (blockIdx.x << 2) | (t >> 6);
        const int lane = t & 63;
        const float4* xr = (const float4*)(x + (size_t)row * K_DIM);
        float4 v[8];
        #pragma unroll
        for (int j = 0; j < 4; j++) {
            v[j]     = xr[(lane << 2) + j];
            v[4 + j] = xr[256 + (lane << 2) + j];
        }
        float m = 0.0f;
        #pragma unroll
        for (int i = 0; i < 8; i++)
            m = fmaxf(m, fmaxf(fmaxf(fabsf(v[i].x), fabsf(v[i].y)),
                               fmaxf(fabsf(v[i].z), fabsf(v[i].w))));
        #pragma unroll
        for (int off = 32; off; off >>= 1) m = fmaxf(m, __shfl_xor(m, off));
        const float scale = fmaxf(m, 1e-5f);
        if (lane == 0) xscale[row] = scale;
        const float rs = 127.0f / scale;            // one divide, 32 multiplies
        v4i* outp = (v4i*)(xq + (size_t)row * K_DIM);
        v4i pk0, pk1;
        #pragma unroll
        for (int j = 0; j < 4; j++) {
            pk0[j] = qclamp(v[j].x * rs, -128, 127)
                   | (qclamp(v[j].y * rs, -128, 127) << 8)
                   | (qclamp(v[j].z * rs, -128, 127) << 16)
                   | (qclamp(v[j].w * rs, -128, 127) << 24);
            pk1[j] = qclamp(v[4 + j].x * rs, -128, 127)
                   | (qclamp(v[4 + j].y * rs, -128, 127) << 8)
                   | (qclamp(v[4 + j].z * rs, -128, 127) << 16)
                   | (qclamp(v[4 + j].w * rs, -128, 127) << 24);
        }
        outp[lane]      = pk0;                      // words 4l..4l+3
        outp[64 + lane] = pk1;                      // words 256+4l..+3
    } else {
        // ---- ternary w-quant, row-major; thread owns 16 consecutive floats ----
        __shared__ double ls0[4], ls1[4];
        double s0 = spart[t] + spart[t + 256];
        double s1 = apart[t] + apart[t + 256];
        #pragma unroll
        for (int off = 32; off; off >>= 1) {
            s0 += __shfl_down(s0, off);
            s1 += __shfl_down(s1, off);
        }
        if ((t & 63) == 0) { ls0[t >> 6] = s0; ls1[t >> 6] = s1; }
        __syncthreads();
        float mean  = (float)((ls0[0] + ls0[1] + ls0[2] + ls0[3]) * (1.0 / (double)W_ELEMS));
        float scale = (float)fmax((ls1[0] + ls1[1] + ls1[2] + ls1[3]) * (1.0 / (double)W_ELEMS), 1e-5);
        const float ri = 1.0f / scale;
        const int i0 = (blockIdx.x - 4096) * 256 + t;   // 0..262143, 16 floats each
        const float4* wp = (const float4*)w + (i0 << 2);
        v4i pk;
        #pragma unroll
        for (int j = 0; j < 4; j++) {
            float4 v = wp[j];
            pk[j] = qclamp((v.x - mean) * ri, -1, 1)
                  | (qclamp((v.y - mean) * ri, -1, 1) << 8)
                  | (qclamp((v.z - mean) * ri, -1, 1) << 16)
                  | (qclamp((v.w - mean) * ri, -1, 1) << 24);
        }
        ((v4i*)wq)[i0] = pk;
        if (i0 == 0) wsf[0] = scale * (1.0f / 127.0f);  // dequant factor for gemm
    }
}

// ---------------- int8 GEMM: R7 verbatim (best measured: 85.6-86.6us) ----------
// 256x256 tile, BK=64, 8 waves, 3 LDS buffers, one barrier + counted vmcnt(4)
// per tile, proven-0-conflict 16-row fragments with chunk-slot swizzle
// s = c ^ ((r>>1)&3) applied on the global source. Plateau accepted after 8
// structural variants (86-96us, MfmaUtil 30-34%).
__global__ __launch_bounds__(512, 2) void gemm_i8_kernel(
    const int8_t* __restrict__ xq, const int8_t* __restrict__ wq,
    const float* __restrict__ xscale, const float* __restrict__ wsf,
    float* __restrict__ out)
{
    __shared__ __align__(16) int8_t lsA[3][16384];   // [buf][row*64 + slot*16]
    __shared__ __align__(16) int8_t lsB[3][16384];

    const int tid  = threadIdx.x;
    const int lane = tid & 63;
    const int wv   = tid >> 6;

    // bijective XCD swizzle: 512 wgs, 64/XCD; XCD x owns bm in [8x,8x+8), bn fastest
    const int flat = blockIdx.x;
    const int nf   = ((flat & 7) << 6) | (flat >> 3);
    const int bm   = nf >> 3;                        // 0..63
    const int bn   = nf & 7;                         // 0..7

    const int sChunk = (((tid & 3) ^ ((tid >> 3) & 3)) << 4);
    const int8_t* gAb = xq + (size_t)(bm * 256 + (tid >> 2)) * K_DIM + sChunk;
    const int8_t* gBb = wq + (size_t)(bn * 256 + (tid >> 2)) * K_DIM + sChunk;

    #define STAGE(NB, T)                                                       \
        do {                                                                   \
            async_load16(gAb + ((size_t)(T) << 6),                       lsA[NB] + tid * 16); \
            async_load16(gAb + ((size_t)(T) << 6) + (size_t)128 * K_DIM, lsA[NB] + 8192 + tid * 16); \
            async_load16(gBb + ((size_t)(T) << 6),                       lsB[NB] + tid * 16); \
            async_load16(gBb + ((size_t)(T) << 6) + (size_t)128 * K_DIM, lsB[NB] + 8192 + tid * 16); \
        } while (0)

    const int wm = (wv >> 2) << 7;                   // 0 / 128
    const int wn = (wv & 3) << 6;                    // 0 / 64 / 128 / 192
    const int fr = lane & 15;
    const int fc = lane >> 4;                        // 16B k-chunk 0..3
    int aoff[8], boff[4];
    #pragma unroll
    for (int mi = 0; mi < 8; mi++) {
        int ra = wm + mi * 16 + fr;
        aoff[mi] = ra * 64 + ((fc ^ ((ra >> 1) & 3)) << 4);
    }
    #pragma unroll
    for (int nj = 0; nj < 4; nj++) {
        int rb = wn + nj * 16 + fr;
        boff[nj] = rb * 64 + ((fc ^ ((rb >> 1) & 3)) << 4);
    }

    v4i acc[8][4] = {};

    #define COMPUTE(CB)                                                        \
        do {                                                                   \
            v4i af[8], bf[4];                                                  \
            _Pragma("unroll")                                                  \
            for (int mi_ = 0; mi_ < 8; mi_++)                                  \
                af[mi_] = *(const v4i*)(lsA[CB] + aoff[mi_]);                  \
            _Pragma("unroll")                                                  \
            for (int nj_ = 0; nj_ < 4; nj_++)                                  \
                bf[nj_] = *(const v4i*)(lsB[CB] + boff[nj_]);                  \
            __builtin_amdgcn_s_setprio(1);                                     \
            _Pragma("unroll")                                                  \
            for (int mi_ = 0; mi_ < 8; mi_++)                                  \
                _Pragma("unroll")                                              \
                for (int nj_ = 0; nj_ < 4; nj_++)                              \
                    acc[mi_][nj_] = __builtin_amdgcn_mfma_i32_16x16x64_i8(     \
                        af[mi_], bf[nj_], acc[mi_][nj_], 0, 0, 0);             \
            __builtin_amdgcn_s_setprio(0);                                     \
        } while (0)

    #define TILE_MID(CB, NB, T)                                                \
        do {                                                                   \
            STAGE(NB, (T) + 2);                                                \
            COMPUTE(CB);                                                       \
            asm volatile("s_waitcnt vmcnt(4)" ::: "memory");                   \
            __builtin_amdgcn_s_barrier();                                      \
        } while (0)

    STAGE(0, 0);
    STAGE(1, 1);
    asm volatile("s_waitcnt vmcnt(4)" ::: "memory");
    __builtin_amdgcn_s_barrier();

    for (int tt = 0; tt < 30; tt += 3) {
        TILE_MID(0, 2, tt);
        TILE_MID(1, 0, tt + 1);
        TILE_MID(2, 1, tt + 2);
    }
    COMPUTE(0);
    asm volatile("s_waitcnt vmcnt(0)" ::: "memory");
    __builtin_amdgcn_s_barrier();
    COMPUTE(1);

    #undef TILE_MID
    #undef COMPUTE
    #undef STAGE

    // epilogue: dequant. 16x16 C/D: col = lane&15, row = (lane>>4)*4 + reg
    const float f127 = wsf[0];
    #pragma unroll
    for (int mi = 0; mi < 8; mi++) {
        #pragma unroll
        for (int rg = 0; rg < 4; rg++) {
            const int mg = bm * 256 + wm + mi * 16 + (lane >> 4) * 4 + rg;
            const float fs = f127 * xscale[mg];
            float* orow = out + (size_t)mg * N_DIM + bn * 256 + wn;
            #pragma unroll
            for (int nj = 0; nj < 4; nj++)
                orow[nj * 16 + fr] = fs * (float)acc[mi][nj][rg];
        }
    }
}

extern "C" void kernel_launch(void* const* d_in, const int* in_sizes, int n_in,
                              void* d_out, int out_size, void* d_ws, size_t ws_size,
                              hipStream_t stream) {
    const float* x = (const float*)d_in[0];
    const float* w = (const float*)d_in[1];
    float* out = (float*)d_out;

    char* ws = (char*)d_ws;
    double* spart  = (double*)ws;                    // 4 KB (512 doubles)
    double* apart  = (double*)(ws + 4096);           // 4 KB
    float*  wsf    = (float*)(ws + 8192);            // 4 B
    float*  xscale = (float*)(ws + 12288);           // 64 KB
    int8_t* xq     = (int8_t*)(ws + 12288 + 65536);  // 32 MB
    int8_t* wq     = xq + (size_t)M_TOT * K_DIM;     // 4 MB (row-major)

    wsum_kernel <<<512, 256, 0, stream>>>(w, spart);
    wabs_kernel <<<512, 256, 0, stream>>>(w, spart, apart);
    quant_kernel<<<5120, 256, 0, stream>>>(x, w, spart, apart, xq, wq, xscale, wsf);
    gemm_i8_kernel<<<512, 512, 0, stream>>>(xq, wq, xscale, wsf, out);
}